// Round 1
// baseline (459.244 us; speedup 1.0000x reference)
//
#include <hip/hip_runtime.h>
#include <hip/hip_bf16.h>

#define C 64
#define EPS 1e-5f

// ---------------------------------------------------------------------------
// Transpose w1 [C][2C] -> w1t [2C][C] so the MLP kernel reads contiguous
// 256B rows at wave-uniform addresses (scalar loads).
// ---------------------------------------------------------------------------
__global__ __launch_bounds__(256) void transpose_w1_kernel(
    const float* __restrict__ w1, float* __restrict__ w1t) {
  int idx = blockIdx.x * 256 + threadIdx.x;  // 64*128 = 8192 elements
  if (idx < C * 2 * C) {
    int c = idx / (2 * C);
    int k = idx % (2 * C);
    w1t[k * C + c] = w1[idx];
  }
}

// ---------------------------------------------------------------------------
// Per-node: LayerNorm -> Dense(2C) -> silu -> Dense(C) -> *vln_weight -> q
// then D[n][i][c] = q[c] * vec[n][i][c].  One thread per node; x_norm and the
// output accumulator live in registers; weights are wave-uniform -> s_loads.
// ---------------------------------------------------------------------------
__global__ __launch_bounds__(256) void node_mlp_kernel(
    const float* __restrict__ x, const float* __restrict__ vec,
    const float* __restrict__ ln_scale, const float* __restrict__ ln_bias,
    const float* __restrict__ vln_w,
    const float* __restrict__ w1t, const float* __restrict__ b1,
    const float* __restrict__ w2, const float* __restrict__ b2,
    float* __restrict__ D, int n_nodes) {
  int n = blockIdx.x * blockDim.x + threadIdx.x;
  if (n >= n_nodes) return;

  const float* xp = x + (size_t)n * C;
  float xr[C];
  float mean = 0.f;
#pragma unroll
  for (int c0 = 0; c0 < C; c0 += 4) {
    float4 v = *(const float4*)(xp + c0);
    xr[c0] = v.x; xr[c0 + 1] = v.y; xr[c0 + 2] = v.z; xr[c0 + 3] = v.w;
    mean += v.x + v.y + v.z + v.w;
  }
  mean *= (1.f / C);
  float var = 0.f;
#pragma unroll
  for (int c = 0; c < C; c++) { float d = xr[c] - mean; var += d * d; }
  var *= (1.f / C);
  float rs = rsqrtf(var + EPS);
#pragma unroll
  for (int c = 0; c < C; c++)
    xr[c] = (xr[c] - mean) * rs * ln_scale[c] + ln_bias[c];

  float out[C];
#pragma unroll
  for (int c = 0; c < C; c++) out[c] = b2[c];

  for (int k = 0; k < 2 * C; k++) {
    const float* wrow = w1t + k * C;   // wave-uniform address -> s_load
    float h = b1[k];
#pragma unroll
    for (int c = 0; c < C; c++) h += xr[c] * wrow[c];
    float sv = h / (1.f + __expf(-h));  // silu
    const float* w2row = w2 + k * C;   // wave-uniform -> s_load
#pragma unroll
    for (int c = 0; c < C; c++) out[c] += sv * w2row[c];
  }

  // q = out * vln_weight (folded so edge kernel sees vln_weight^2 correctly)
#pragma unroll
  for (int c = 0; c < C; c++) out[c] *= vln_w[c];

  const float* vp = vec + (size_t)n * 3 * C;
  float* Dp = D + (size_t)n * 3 * C;
#pragma unroll
  for (int ic = 0; ic < 3 * C; ic += 4) {
    float4 v = *(const float4*)(vp + ic);
    float4 o;
    o.x = v.x * out[(ic + 0) & (C - 1)];
    o.y = v.y * out[(ic + 1) & (C - 1)];
    o.z = v.z * out[(ic + 2) & (C - 1)];
    o.w = v.w * out[(ic + 3) & (C - 1)];
    *(float4*)(Dp + ic) = o;
  }
}

// ---------------------------------------------------------------------------
// Per-edge: one wave per edge, lane = channel.
// dE[c] = sum_i D[r][i][c] * sum_j M[i][j] * D[s][j][c];  atomicAdd into dx[r].
// ---------------------------------------------------------------------------
__global__ __launch_bounds__(256) void edge_kernel(
    const int* __restrict__ senders, const int* __restrict__ receivers,
    const float* __restrict__ Mmat, const float* __restrict__ D,
    float* __restrict__ dx, int n_edges) {
  int wid = threadIdx.x >> 6;
  int lane = threadIdx.x & 63;
  int e = blockIdx.x * 4 + wid;
  if (e >= n_edges) return;
  e = __builtin_amdgcn_readfirstlane(e);  // provably wave-uniform -> scalar

  int r = receivers[e];
  int s = senders[e];
  const float* M = Mmat + (size_t)e * 9;  // uniform -> s_loads into SGPRs
  float m00 = M[0], m01 = M[1], m02 = M[2];
  float m10 = M[3], m11 = M[4], m12 = M[5];
  float m20 = M[6], m21 = M[7], m22 = M[8];

  const float* Dr = D + (size_t)r * (3 * C);
  const float* Ds = D + (size_t)s * (3 * C);
  float ds0 = Ds[lane], ds1 = Ds[C + lane], ds2 = Ds[2 * C + lane];
  float dr0 = Dr[lane], dr1 = Dr[C + lane], dr2 = Dr[2 * C + lane];

  float f0 = m00 * ds0 + m01 * ds1 + m02 * ds2;
  float f1 = m10 * ds0 + m11 * ds1 + m12 * ds2;
  float f2 = m20 * ds0 + m21 * ds1 + m22 * ds2;
  float dE = dr0 * f0 + dr1 * f1 + dr2 * f2;

  atomicAdd(dx + (size_t)r * C + lane, dE);
}

// ---------------------------------------------------------------------------
extern "C" void kernel_launch(void* const* d_in, const int* in_sizes, int n_in,
                              void* d_out, int out_size, void* d_ws, size_t ws_size,
                              hipStream_t stream) {
  const float* x        = (const float*)d_in[0];
  const float* vec      = (const float*)d_in[1];
  const int*   senders  = (const int*)d_in[2];
  const int*   receivers= (const int*)d_in[3];
  const float* Mmat     = (const float*)d_in[4];
  const float* ln_scale = (const float*)d_in[5];
  const float* ln_bias  = (const float*)d_in[6];
  const float* vln_w    = (const float*)d_in[7];
  const float* w1       = (const float*)d_in[8];
  const float* b1       = (const float*)d_in[9];
  const float* w2       = (const float*)d_in[10];
  const float* b2       = (const float*)d_in[11];
  float* dx = (float*)d_out;

  int n_nodes = in_sizes[0] / C;   // 50000
  int n_edges = in_sizes[2];       // 800000

  // Workspace layout: w1t (2C*C floats = 32 KB), then D [N][3][C] (38.4 MB)
  float* w1t = (float*)d_ws;
  float* D   = w1t + 2 * C * C;

  // 1. transpose w1
  transpose_w1_kernel<<<(C * 2 * C + 255) / 256, 256, 0, stream>>>(w1, w1t);

  // 2. per-node MLP -> D
  node_mlp_kernel<<<(n_nodes + 255) / 256, 256, 0, stream>>>(
      x, vec, ln_scale, ln_bias, vln_w, w1t, b1, w2, b2, D, n_nodes);

  // 3. zero dx (harness poisons d_out), then edge accumulation
  hipMemsetAsync(d_out, 0, (size_t)out_size * sizeof(float), stream);
  edge_kernel<<<(n_edges + 3) / 4, 256, 0, stream>>>(
      senders, receivers, Mmat, D, dx, n_edges);
}

// Round 2
// 370.374 us; speedup vs baseline: 1.2399x; 1.2399x over previous
//
#include <hip/hip_runtime.h>
#include <hip/hip_bf16.h>

#define C 64
#define EPS 1e-5f

// ---- bf16 pack/unpack helpers (RNE) ---------------------------------------
static __device__ __forceinline__ unsigned int f2bf(float f) {
  unsigned int x = __float_as_uint(f);
  return (x + 0x7fffu + ((x >> 16) & 1u)) >> 16;
}
static __device__ __forceinline__ float bflo2f(unsigned int p) {  // low ushort
  return __uint_as_float(p << 16);
}
static __device__ __forceinline__ float bfhi2f(unsigned int p) {  // high ushort
  return __uint_as_float(p & 0xffff0000u);
}

// ---------------------------------------------------------------------------
// Build w1 interleaved: w1i[(k/4)*4C + c*4 + (k%4)] = w1[c][k]
// so layer-1 reads one float4 = w1[c][k0..k0+3] per (c, k-group).
// ---------------------------------------------------------------------------
__global__ __launch_bounds__(256) void build_w1i_kernel(
    const float* __restrict__ w1, float* __restrict__ w1i) {
  int idx = blockIdx.x * 256 + threadIdx.x;  // 64*128 = 8192
  if (idx < C * 2 * C) {
    int c = idx / (2 * C);
    int k = idx % (2 * C);
    w1i[(k >> 2) * (4 * C) + c * 4 + (k & 3)] = w1[idx];
  }
}

// ---------------------------------------------------------------------------
// Per-node: LayerNorm -> Dense(2C) -> silu -> Dense(C) -> *vln_weight -> q
// D16[n][c] = {bf16(q*vec0), bf16(q*vec1), bf16(q*vec2), 0} packed in uint2.
// Thread per node; weights in LDS, all threads read same address (broadcast).
// Layer1: 4 independent h accumulators; layer2: 64 independent accumulators.
// ---------------------------------------------------------------------------
__global__ __launch_bounds__(256, 1) void node_mlp_kernel(
    const float* __restrict__ x, const float* __restrict__ vec,
    const float* __restrict__ ln_scale, const float* __restrict__ ln_bias,
    const float* __restrict__ vln_w,
    const float* __restrict__ w1i, const float* __restrict__ b1,
    const float* __restrict__ w2, const float* __restrict__ b2,
    uint2* __restrict__ D16, int n_nodes) {
  __shared__ float w1s[2 * C * C];  // [k/4][c][4]
  __shared__ float w2s[2 * C * C];  // [k][c]
  {
    float4* d1 = (float4*)w1s;
    const float4* s1 = (const float4*)w1i;
    float4* d2 = (float4*)w2s;
    const float4* s2 = (const float4*)w2;
    for (int i = threadIdx.x; i < 2 * C * C / 4; i += 256) {
      d1[i] = s1[i];
      d2[i] = s2[i];
    }
  }
  __syncthreads();

  int n = blockIdx.x * 256 + threadIdx.x;
  if (n >= n_nodes) return;

  // ---- LayerNorm ----
  const float* xp = x + (size_t)n * C;
  float xr[C];
  float mean = 0.f;
#pragma unroll
  for (int c0 = 0; c0 < C; c0 += 4) {
    float4 v = *(const float4*)(xp + c0);
    xr[c0] = v.x; xr[c0 + 1] = v.y; xr[c0 + 2] = v.z; xr[c0 + 3] = v.w;
    mean += v.x + v.y + v.z + v.w;
  }
  mean *= (1.f / C);
  float var = 0.f;
#pragma unroll
  for (int c = 0; c < C; c++) { float d = xr[c] - mean; var += d * d; }
  var *= (1.f / C);
  float rs = rsqrtf(var + EPS);
#pragma unroll
  for (int c = 0; c < C; c++)
    xr[c] = (xr[c] - mean) * rs * ln_scale[c] + ln_bias[c];

  // ---- MLP ----
  float out[C];
#pragma unroll
  for (int c = 0; c < C; c++) out[c] = b2[c];

  for (int k0 = 0; k0 < 2 * C; k0 += 4) {
    float h0 = b1[k0], h1 = b1[k0 + 1], h2 = b1[k0 + 2], h3 = b1[k0 + 3];
    const float4* wrow = (const float4*)(w1s + k0 * C);  // [c][4]
#pragma unroll
    for (int c = 0; c < C; c++) {
      float4 w = wrow[c];  // LDS broadcast (all lanes same addr)
      float xc = xr[c];
      h0 = fmaf(xc, w.x, h0);
      h1 = fmaf(xc, w.y, h1);
      h2 = fmaf(xc, w.z, h2);
      h3 = fmaf(xc, w.w, h3);
    }
    float sv[4];
    sv[0] = h0 / (1.f + __expf(-h0));
    sv[1] = h1 / (1.f + __expf(-h1));
    sv[2] = h2 / (1.f + __expf(-h2));
    sv[3] = h3 / (1.f + __expf(-h3));
#pragma unroll
    for (int j = 0; j < 4; j++) {
      const float4* w2row = (const float4*)(w2s + (k0 + j) * C);
      float s = sv[j];
#pragma unroll
      for (int c0 = 0; c0 < C / 4; c0++) {
        float4 w = w2row[c0];  // LDS broadcast
        out[c0 * 4 + 0] = fmaf(s, w.x, out[c0 * 4 + 0]);
        out[c0 * 4 + 1] = fmaf(s, w.y, out[c0 * 4 + 1]);
        out[c0 * 4 + 2] = fmaf(s, w.z, out[c0 * 4 + 2]);
        out[c0 * 4 + 3] = fmaf(s, w.w, out[c0 * 4 + 3]);
      }
    }
  }

  // fold vln_weight into q
#pragma unroll
  for (int c = 0; c < C; c++) out[c] *= vln_w[c];

  // ---- D = q * vec, packed bf16 [n][c][{0,1,2,pad}] ----
  const float* vp = vec + (size_t)n * 3 * C;
  uint2* Dp = D16 + (size_t)n * C;
#pragma unroll
  for (int c0 = 0; c0 < C / 4; c0++) {
    float4 v0 = *(const float4*)(vp + c0 * 4);           // comp 0
    float4 v1 = *(const float4*)(vp + C + c0 * 4);       // comp 1
    float4 v2 = *(const float4*)(vp + 2 * C + c0 * 4);   // comp 2
    float q0 = out[c0 * 4 + 0], q1 = out[c0 * 4 + 1];
    float q2 = out[c0 * 4 + 2], q3 = out[c0 * 4 + 3];
    uint2 u;
    u.x = f2bf(q0 * v0.x) | (f2bf(q0 * v1.x) << 16);
    u.y = f2bf(q0 * v2.x);
    Dp[c0 * 4 + 0] = u;
    u.x = f2bf(q1 * v0.y) | (f2bf(q1 * v1.y) << 16);
    u.y = f2bf(q1 * v2.y);
    Dp[c0 * 4 + 1] = u;
    u.x = f2bf(q2 * v0.z) | (f2bf(q2 * v1.z) << 16);
    u.y = f2bf(q2 * v2.z);
    Dp[c0 * 4 + 2] = u;
    u.x = f2bf(q3 * v0.w) | (f2bf(q3 * v1.w) << 16);
    u.y = f2bf(q3 * v2.w);
    Dp[c0 * 4 + 3] = u;
  }
}

// ---------------------------------------------------------------------------
// Per-edge: wave handles 4 edges, lane = channel. One dwordx2 gather per
// node-row (all 3 components packed bf16). M + indices via scalar loads.
// ---------------------------------------------------------------------------
__global__ __launch_bounds__(256) void edge_kernel(
    const int* __restrict__ senders, const int* __restrict__ receivers,
    const float* __restrict__ Mmat, const uint2* __restrict__ D2,
    float* __restrict__ dx, int n_edges) {
  int wid = threadIdx.x >> 6;
  int lane = threadIdx.x & 63;
  int e0 = (blockIdx.x * 4 + wid) * 4;
  if (e0 >= n_edges) return;
  e0 = __builtin_amdgcn_readfirstlane(e0);
  int nvalid = n_edges - e0;  // >=1; usually >=4

  int r[4], s[4];
#pragma unroll
  for (int j = 0; j < 4; j++) {
    int e = (j < nvalid) ? e0 + j : e0;  // clamp: keeps loads in-bounds
    r[j] = receivers[e];
    s[j] = senders[e];
  }
  uint2 dsv[4], drv[4];
#pragma unroll
  for (int j = 0; j < 4; j++) {
    dsv[j] = D2[(size_t)s[j] * C + lane];
    drv[j] = D2[(size_t)r[j] * C + lane];
  }
#pragma unroll
  for (int j = 0; j < 4; j++) {
    if (j < nvalid) {
      const float* M = Mmat + (size_t)(e0 + j) * 9;  // uniform -> s_load
      float m00 = M[0], m01 = M[1], m02 = M[2];
      float m10 = M[3], m11 = M[4], m12 = M[5];
      float m20 = M[6], m21 = M[7], m22 = M[8];
      float s0 = bflo2f(dsv[j].x), s1 = bfhi2f(dsv[j].x), s2 = bflo2f(dsv[j].y);
      float r0 = bflo2f(drv[j].x), r1 = bfhi2f(drv[j].x), r2 = bflo2f(drv[j].y);
      float f0 = m00 * s0 + m01 * s1 + m02 * s2;
      float f1 = m10 * s0 + m11 * s1 + m12 * s2;
      float f2 = m20 * s0 + m21 * s1 + m22 * s2;
      float dE = r0 * f0 + r1 * f1 + r2 * f2;
      atomicAdd(dx + (size_t)r[j] * C + lane, dE);
    }
  }
}

// ---------------------------------------------------------------------------
extern "C" void kernel_launch(void* const* d_in, const int* in_sizes, int n_in,
                              void* d_out, int out_size, void* d_ws, size_t ws_size,
                              hipStream_t stream) {
  const float* x        = (const float*)d_in[0];
  const float* vec      = (const float*)d_in[1];
  const int*   senders  = (const int*)d_in[2];
  const int*   receivers= (const int*)d_in[3];
  const float* Mmat     = (const float*)d_in[4];
  const float* ln_scale = (const float*)d_in[5];
  const float* ln_bias  = (const float*)d_in[6];
  const float* vln_w    = (const float*)d_in[7];
  const float* w1       = (const float*)d_in[8];
  const float* b1       = (const float*)d_in[9];
  const float* w2       = (const float*)d_in[10];
  const float* b2       = (const float*)d_in[11];
  float* dx = (float*)d_out;

  int n_nodes = in_sizes[0] / C;   // 50000
  int n_edges = in_sizes[2];       // 800000

  // Workspace: w1i (8192 floats = 32 KB), then D16 [N][C] uint2 (25.6 MB)
  float* w1i = (float*)d_ws;
  uint2* D16 = (uint2*)(w1i + 2 * C * C);

  build_w1i_kernel<<<(C * 2 * C + 255) / 256, 256, 0, stream>>>(w1, w1i);

  node_mlp_kernel<<<(n_nodes + 255) / 256, 256, 0, stream>>>(
      x, vec, ln_scale, ln_bias, vln_w, w1i, b1, w2, b2, D16, n_nodes);

  hipMemsetAsync(d_out, 0, (size_t)out_size * sizeof(float), stream);

  edge_kernel<<<(n_edges + 15) / 16, 256, 0, stream>>>(
      senders, receivers, Mmat, D16, dx, n_edges);
}